// Round 14
// baseline (128.887 us; speedup 1.0000x reference)
//
#include <hip/hip_runtime.h>

#define NCLS 80
#define MAXB 20
#define N0 27648     // 96*96*3
#define N1 110592    // 192*192*3
#define NTOT (N0 + N1)
#define CAP 8192       // per-class candidate capacity in workspace
#define DT 512         // block size
#define NBLK (NTOT / DT)   // 270 blocks; co-residency proven by r8 coop launch
#define DSTAGE 3072    // per-block candidate staging (expected ~1122, +59 sigma)
#define CNT_STRIDE 16  // pad class counters to one 64B line each
#define NB 256         // score histogram buckets ((bits-0.6f)>>15, max 204)
#define TARGET 64      // top-k cut for fast NMS path (exact via fallback)
#define SCAP 256       // compact-list capacity (4 slots/lane in wave 0)

__device__ __forceinline__ float sigf(float x) {
    return 1.0f / (1.0f + expf(-x));
}

// ---- DPP wave64 primitives (proven exact rounds 5-13, absmax 0) ----
__device__ __forceinline__ unsigned wave_max_bcast(unsigned x) {
    unsigned t;
    t = (unsigned)__builtin_amdgcn_update_dpp((int)x, (int)x, 0x111, 0xF, 0xF, false); x = x > t ? x : t;
    t = (unsigned)__builtin_amdgcn_update_dpp((int)x, (int)x, 0x112, 0xF, 0xF, false); x = x > t ? x : t;
    t = (unsigned)__builtin_amdgcn_update_dpp((int)x, (int)x, 0x114, 0xF, 0xF, false); x = x > t ? x : t;
    t = (unsigned)__builtin_amdgcn_update_dpp((int)x, (int)x, 0x118, 0xF, 0xF, false); x = x > t ? x : t;
    t = (unsigned)__builtin_amdgcn_update_dpp((int)x, (int)x, 0x142, 0xF, 0xF, false); x = x > t ? x : t;
    t = (unsigned)__builtin_amdgcn_update_dpp((int)x, (int)x, 0x143, 0xF, 0xF, false); x = x > t ? x : t;
    return (unsigned)__builtin_amdgcn_readlane((int)x, 63);
}

__device__ __forceinline__ unsigned wave_min_bcast(unsigned x) {
    unsigned t;
    t = (unsigned)__builtin_amdgcn_update_dpp((int)x, (int)x, 0x111, 0xF, 0xF, false); x = x < t ? x : t;
    t = (unsigned)__builtin_amdgcn_update_dpp((int)x, (int)x, 0x112, 0xF, 0xF, false); x = x < t ? x : t;
    t = (unsigned)__builtin_amdgcn_update_dpp((int)x, (int)x, 0x114, 0xF, 0xF, false); x = x < t ? x : t;
    t = (unsigned)__builtin_amdgcn_update_dpp((int)x, (int)x, 0x118, 0xF, 0xF, false); x = x < t ? x : t;
    t = (unsigned)__builtin_amdgcn_update_dpp((int)x, (int)x, 0x142, 0xF, 0xF, false); x = x < t ? x : t;
    t = (unsigned)__builtin_amdgcn_update_dpp((int)x, (int)x, 0x143, 0xF, 0xF, false); x = x < t ? x : t;
    return (unsigned)__builtin_amdgcn_readlane((int)x, 63);
}

// Wave64 inclusive +scan (LLVM AtomicOptimizer idiom).
__device__ __forceinline__ unsigned wave_incl_scan(unsigned x) {
    x += (unsigned)__builtin_amdgcn_update_dpp(0, (int)x, 0x111, 0xF, 0xF, false);
    x += (unsigned)__builtin_amdgcn_update_dpp(0, (int)x, 0x112, 0xF, 0xF, false);
    x += (unsigned)__builtin_amdgcn_update_dpp(0, (int)x, 0x114, 0xF, 0xF, false);
    x += (unsigned)__builtin_amdgcn_update_dpp(0, (int)x, 0x118, 0xF, 0xF, false);
    x += (unsigned)__builtin_amdgcn_update_dpp(0, (int)x, 0x142, 0xA, 0xF, false);
    x += (unsigned)__builtin_amdgcn_update_dpp(0, (int)x, 0x143, 0xC, 0xF, false);
    return x;
}

// Fused r13 decode + spin barrier + r13 NMS (blocks 0..79).
// Barrier: threadfence-reduction pattern — all threads fence, sync, thread 0
// release-adds `done`; blocks >= NCLS exit immediately; blocks < NCLS spin
// (acquire + s_sleep) until done==NBLK, then acquire-fence and run NMS.
// Co-residency (270 blocks, 8 waves, ~51KB LDS -> 3 blocks/CU cap) was
// hardware-validated by r8's cooperative launch of the same geometry.
__global__ __launch_bounds__(DT) void fused_kernel(
    const float* __restrict__ feats0, const float* __restrict__ feats1,
    float4* __restrict__ boxes, uint2* __restrict__ cands,
    int* __restrict__ counts, int* __restrict__ done,
    float* __restrict__ out)
{
    // decode LDS
    __shared__ unsigned p_gi[DT];
    __shared__ float    p_conf[DT];
    __shared__ int s_npass;
    __shared__ float    s_esc[DSTAGE];
    __shared__ unsigned s_ent[DSTAGE];       // gi | (class<<18)
    __shared__ unsigned short s_lp[DSTAGE];  // per-class local position
    __shared__ int s_n;
    __shared__ int s_cnt[NCLS];
    __shared__ int s_base[NCLS];
    // NMS LDS
    __shared__ int s_hist[NB];
    __shared__ int s_tau;
    __shared__ int s_m;
    __shared__ float4   s_cbox[SCAP];
    __shared__ unsigned s_csc[SCAP];
    __shared__ unsigned s_cix[SCAP];
    __shared__ unsigned char s_alive[CAP];   // fallback only

    int tid = threadIdx.x;
    int blk = blockIdx.x;
    if (tid == 0) { s_npass = 0; s_n = 0; }
    if (tid < NCLS) s_cnt[tid] = 0;
    __syncthreads();

    const float* feats;
    int S, base, i;
    float aw0, ah0, aw1, ah1, aw2, ah2;
    if (blk < N0 / DT) {
        feats = feats0; S = 96; base = 0;
        i = blk * DT + tid;
        aw0 = 81.0f;  ah0 = 82.0f;  aw1 = 135.0f; ah1 = 169.0f; aw2 = 344.0f; ah2 = 319.0f;
    } else {
        feats = feats1; S = 192; base = N0;
        i = (blk - N0 / DT) * DT + tid;
        aw0 = 23.0f;  ah0 = 27.0f;  aw1 = 37.0f;  ah1 = 58.0f;  aw2 = 81.0f;  ah2 = 82.0f;
    }

    // ---- phase 0: gate + inline box decode/write (r13, proven) ----
    const float* f = feats + (size_t)i * 85;
    float4 head = *reinterpret_cast<const float4*>(f);   // tx,ty,tw,th
    float sconf = sigf(f[4]);
    if (sconf >= 0.6f) {   // sconf < 0.6 => all class scores < 0.6 (exact)
        int sl = atomicAdd(&s_npass, 1);   // <= DT
        p_gi[sl] = (unsigned)(base + i);
        p_conf[sl] = sconf;

        int a = i % 3;
        int cell = i / 3;
        int gx = cell % S;
        int gy = cell / S;

        float Sf = (float)S;
        float inpf = Sf * 32.0f;
        float aw = (a == 0) ? aw0 : ((a == 1) ? aw1 : aw2);
        float ah = (a == 0) ? ah0 : ((a == 1) ? ah1 : ah2);

        float x = (sigf(head.x) + (float)gx) / Sf;
        float y = (sigf(head.y) + (float)gy) / Sf;
        float w = expf(head.z) * aw / inpf;
        float h = expf(head.w) * ah / inpf;

        // yolo_correct_boxes: letterbox constants identical for both layers
        const float OFF = 0.21875f;
        const float SC  = 3072.0f / 1728.0f;
        float yy = (y - OFF) * SC;
        float hh = h * SC;

        boxes[base + i] = make_float4((yy - hh * 0.5f) * 1080.0f,
                                      (x  - w  * 0.5f) * 1920.0f,
                                      (yy + hh * 0.5f) * 1080.0f,
                                      (x  + w  * 0.5f) * 1920.0f);
    }
    __syncthreads();

    int npass = s_npass;

    // ---- phase 1: dense (pass-anchor, 4-class-group) emission, 4-deep MLP ----
    int tot = npass * (NCLS / 4);
    for (int wk0 = tid; wk0 < tot; wk0 += DT * 4) {
        float4   pv[4];
        unsigned gi4[4];
        float    cf[4];
        int      g4[4];
#pragma unroll
        for (int j = 0; j < 4; ++j) {
            int wk = wk0 + j * DT;
            if (wk < tot) {
                int sl = wk / (NCLS / 4);
                int g  = wk - sl * (NCLS / 4);
                gi4[j] = p_gi[sl];
                cf[j] = p_conf[sl];
                g4[j] = g;
                pv[j] = *reinterpret_cast<const float4*>(
                    feats + (size_t)(gi4[j] - (unsigned)base) * 85 + 5 + g * 4);
            }
        }
#pragma unroll
        for (int j = 0; j < 4; ++j) {
            int wk = wk0 + j * DT;
            if (wk < tot) {
#pragma unroll
                for (int q = 0; q < 4; ++q) {
                    float pj = (q == 0) ? pv[j].x : (q == 1) ? pv[j].y
                             : (q == 2) ? pv[j].z : pv[j].w;
                    float s = cf[j] * sigf(pj);
                    if (s >= 0.6f) {
                        int c = g4[j] * 4 + q;
                        int e = atomicAdd(&s_n, 1);
                        int lp = atomicAdd(&s_cnt[c], 1);
                        if (e < DSTAGE) {
                            s_esc[e] = s;
                            s_ent[e] = gi4[j] | ((unsigned)c << 18);
                            s_lp[e] = (unsigned short)lp;
                        }
                    }
                }
            }
        }
    }
    __syncthreads();

    int n = s_n < DSTAGE ? s_n : DSTAGE;

    // ---- phase 2: one reserve atomic per (block,class), padded lines ----
    if (tid < NCLS) {
        int k = s_cnt[tid];
        s_base[tid] = (k > 0) ? atomicAdd(&counts[tid * CNT_STRIDE], k) : 0;
    }
    __syncthreads();

    // ---- phase 3: scatter into reserved slices (no atomics) ----
    for (int e = tid; e < n; e += DT) {
        unsigned ent = s_ent[e];
        int c = ent >> 18;
        int pos = s_base[c] + (int)s_lp[e];
        if (pos < CAP)
            cands[(size_t)c * CAP + pos] =
                make_uint2(__float_as_uint(s_esc[e]), ent & 0x3FFFFu);
    }

    // ---- device-wide barrier (threadfence-reduction pattern) ----
    __threadfence();       // all threads: release block's global writes
    __syncthreads();
    if (tid == 0) {
        __hip_atomic_fetch_add(done, 1, __ATOMIC_ACQ_REL, __HIP_MEMORY_SCOPE_AGENT);
        if (blk < NCLS) {
            while (__hip_atomic_load(done, __ATOMIC_ACQUIRE,
                                     __HIP_MEMORY_SCOPE_AGENT) < NBLK)
                __builtin_amdgcn_s_sleep(2);
        }
    }
    if (blk >= NCLS) return;       // 190 blocks exit, freeing CUs
    __syncthreads();
    __threadfence();               // acquire side: invalidate stale caches

    // ---- NMS for class c = blk (r13 body, 512-thread strides) ----
    int c = blk;

    int cnt = counts[c * CNT_STRIDE];
    if (cnt > CAP) cnt = CAP;

    const uint2* cl = cands + (size_t)c * CAP;

    if (tid < NB) s_hist[tid] = 0;
    if (tid == 0) s_m = 0;
    __syncthreads();

    for (int e0 = tid; e0 < cnt; e0 += DT * 4) {
        unsigned sc4[4];
#pragma unroll
        for (int j = 0; j < 4; ++j) {
            int e = e0 + j * DT;
            if (e < cnt) sc4[j] = cl[e].x;
        }
#pragma unroll
        for (int j = 0; j < 4; ++j) {
            int e = e0 + j * DT;
            if (e < cnt)
                atomicAdd(&s_hist[(sc4[j] - 0x3F199999u) >> 15], 1);
        }
    }
    __syncthreads();

    if (tid < 64) {
        // wave 0: tau = max bucket with cum-from-top >= TARGET (exact)
        unsigned acc = 0;
        bool found = false;
        for (int ch = NB / 64 - 1; ch >= 0 && !found; --ch) {
            unsigned h = (unsigned)s_hist[ch * 64 + tid];
            unsigned incl = wave_incl_scan(h);
            unsigned total = (unsigned)__builtin_amdgcn_readlane((int)incl, 63);
            bool ok = acc + (total - incl + h) >= (unsigned)TARGET;
            unsigned long long mk = __ballot(ok);
            if (mk) {
                if (tid == 0) s_tau = ch * 64 + (63 - __builtin_clzll(mk));
                found = true;
            }
            acc += total;
        }
        if (!found && tid == 0) s_tau = 0;   // take all (total < TARGET)
    }
    __syncthreads();

    int tau = s_tau;
    for (int e0 = tid; e0 < cnt; e0 += DT * 4) {
        uint2 v4[4];
#pragma unroll
        for (int j = 0; j < 4; ++j) {
            int e = e0 + j * DT;
            if (e < cnt) v4[j] = cl[e];
        }
#pragma unroll
        for (int j = 0; j < 4; ++j) {
            int e = e0 + j * DT;
            if (e < cnt && (int)((v4[j].x - 0x3F199999u) >> 15) >= tau) {
                int p = atomicAdd(&s_m, 1);
                if (p < SCAP) {
                    s_csc[p] = v4[j].x;
                    s_cix[p] = v4[j].y;
                    s_cbox[p] = boxes[v4[j].y];
                }
            }
        }
    }
    __syncthreads();

    if (tid >= 64) return;          // only wave 0 continues (no more barriers)

    int lane = tid;
    int m = s_m;
    bool need_fb = (m > SCAP);
    if (m > SCAP) m = SCAP;

    float* ob  = out;             // 1600 boxes * 4
    float* os  = out + 6400;      // 1600 scores
    float* ocl = out + 8000;      // 1600 classes (as float)

    int sel = 0;

    if (!need_fb) {
        unsigned scu[4], ixu[4];
        float4 bx[4];
        float  ar[4];
#pragma unroll
        for (int k = 0; k < 4; ++k) {
            int e = lane + k * 64;
            scu[k] = 0u; ixu[k] = 0xFFFFFFFFu;
            bx[k] = make_float4(0.f, 0.f, 0.f, 0.f);
            ar[k] = 0.f;
            if (e < m) {
                scu[k] = s_csc[e];
                ixu[k] = s_cix[e];
                bx[k] = s_cbox[e];
                ar[k] = (bx[k].z - bx[k].x) * (bx[k].w - bx[k].y);
            }
        }

        for (; sel < MAXB; ++sel) {
            unsigned lm = 0u;
#pragma unroll
            for (int k = 0; k < 4; ++k) lm = lm > scu[k] ? lm : scu[k];
            unsigned smax = wave_max_bcast(lm);
            if (smax == 0u) {
                if (m < cnt) need_fb = true;   // compact list exhausted early
                break;
            }
            unsigned li = 0xFFFFFFFFu;
#pragma unroll
            for (int k = 0; k < 4; ++k)
                if (scu[k] == smax && ixu[k] < li) li = ixu[k];
            unsigned bidx = wave_min_bcast(li);

            bool has = false;
            float4 ob_ = make_float4(0.f, 0.f, 0.f, 0.f);
#pragma unroll
            for (int k = 0; k < 4; ++k)
                if (scu[k] == smax && ixu[k] == bidx) { ob_ = bx[k]; has = true; }
            unsigned long long mk = __ballot(has);
            int src = __ffsll((long long)mk) - 1;
            float4 sb;
            sb.x = __int_as_float(__builtin_amdgcn_readlane(__float_as_int(ob_.x), src));
            sb.y = __int_as_float(__builtin_amdgcn_readlane(__float_as_int(ob_.y), src));
            sb.z = __int_as_float(__builtin_amdgcn_readlane(__float_as_int(ob_.z), src));
            sb.w = __int_as_float(__builtin_amdgcn_readlane(__float_as_int(ob_.w), src));
            float area_s = (sb.z - sb.x) * (sb.w - sb.y);

            if (lane == 0) {
                int o = c * MAXB + sel;
                ob[o * 4 + 0] = sb.x; ob[o * 4 + 1] = sb.y;
                ob[o * 4 + 2] = sb.z; ob[o * 4 + 3] = sb.w;
                os[o]  = __uint_as_float(smax);
                ocl[o] = (float)c;
            }

#pragma unroll
            for (int k = 0; k < 4; ++k) {
                if (scu[k] != 0u) {
                    float y1 = fmaxf(sb.x, bx[k].x);
                    float x1 = fmaxf(sb.y, bx[k].y);
                    float y2 = fminf(sb.z, bx[k].z);
                    float x2 = fminf(sb.w, bx[k].w);
                    float inter = fmaxf(y2 - y1, 0.f) * fmaxf(x2 - x1, 0.f);
                    float un = area_s + ar[k] - inter;
                    float iou = (un > 0.f) ? (inter / un) : 0.f;
                    if (iou > 0.5f || ixu[k] == bidx) scu[k] = 0u;
                }
            }
        }
    }

    if (need_fb) {
        // exact full-list greedy NMS from scratch (statistically never taken)
        for (int e = lane; e < cnt; e += 64) s_alive[e] = 1;
        sel = 0;
        for (; sel < MAXB; ++sel) {
            unsigned bs = 0u, bi = 0xFFFFFFFFu;
            for (int e = lane; e < cnt; e += 64) {
                if (s_alive[e]) {
                    uint2 v = cl[e];
                    if (v.x > bs || (v.x == bs && v.y < bi)) { bs = v.x; bi = v.y; }
                }
            }
            unsigned smax = wave_max_bcast(bs);
            if (smax == 0u) break;
            unsigned li = (bs == smax) ? bi : 0xFFFFFFFFu;
            unsigned bidx = wave_min_bcast(li);

            float4 sb = boxes[bidx];
            float area_s = (sb.z - sb.x) * (sb.w - sb.y);

            if (lane == 0) {
                int o = c * MAXB + sel;
                ob[o * 4 + 0] = sb.x; ob[o * 4 + 1] = sb.y;
                ob[o * 4 + 2] = sb.z; ob[o * 4 + 3] = sb.w;
                os[o]  = __uint_as_float(smax);
                ocl[o] = (float)c;
            }

            for (int e = lane; e < cnt; e += 64) {
                if (s_alive[e]) {
                    uint2 v = cl[e];
                    float4 cb = boxes[v.y];
                    float y1 = fmaxf(sb.x, cb.x);
                    float x1 = fmaxf(sb.y, cb.y);
                    float y2 = fminf(sb.z, cb.z);
                    float x2 = fminf(sb.w, cb.w);
                    float inter = fmaxf(y2 - y1, 0.f) * fmaxf(x2 - x1, 0.f);
                    float area_c = (cb.z - cb.x) * (cb.w - cb.y);
                    float un = area_s + area_c - inter;
                    float iou = (un > 0.f) ? (inter / un) : 0.f;
                    if (iou > 0.5f || v.y == bidx) s_alive[e] = 0;
                }
            }
        }
    }

    // invalid slots: zero boxes/scores, class = -1 (lane-parallel)
    for (int q = sel + lane; q < MAXB; q += 64) {
        int o = c * MAXB + q;
        ob[o * 4 + 0] = 0.0f; ob[o * 4 + 1] = 0.0f;
        ob[o * 4 + 2] = 0.0f; ob[o * 4 + 3] = 0.0f;
        os[o]  = 0.0f;
        ocl[o] = -1.0f;
    }
}

extern "C" void kernel_launch(void* const* d_in, const int* in_sizes, int n_in,
                              void* d_out, int out_size, void* d_ws, size_t ws_size,
                              hipStream_t stream) {
    const float* feats0 = (const float*)d_in[0];
    const float* feats1 = (const float*)d_in[1];
    float* out = (float*)d_out;

    char* ws = (char*)d_ws;
    float4* boxes  = (float4*)ws;                      // NTOT*16B = 2,211,840
    int*    counts = (int*)(ws + 2211840);             // 80*16*4B = 5120
    int*    done   = (int*)(ws + 2211840 + 5120);      // 4B barrier counter
    uint2*  cands  = (uint2*)(ws + 2211840 + 8192);    // 80*CAP*8B = 5.24MB

    // zero counts + done (single small fill node, re-runs every replay)
    hipMemsetAsync(ws + 2211840, 0, 8192, stream);

    fused_kernel<<<NBLK, DT, 0, stream>>>(feats0, feats1, boxes, cands,
                                          counts, done, out);
}

// Round 15
// 42.139 us; speedup vs baseline: 3.0586x; 3.0586x over previous
//
#include <hip/hip_runtime.h>

#define NCLS 80
#define MAXB 20
#define N0 27648     // 96*96*3
#define N1 110592    // 192*192*3
#define NTOT (N0 + N1)
#define CAP 8192       // per-class candidate capacity in workspace
#define DT 512         // decode block size
#define DSTAGE 3072    // per-block candidate staging (expected ~1122, +59 sigma)
#define CNT_STRIDE 16  // pad class counters to one 64B line each
#define NMS_T 1024
#define NB 256         // score histogram buckets ((bits-0.6f)>>15, max 204)
#define TARGET 64      // top-k cut for fast NMS path (exact via fallback)
#define SCAP 256       // compact-list capacity (4 slots/lane in wave 0)

__device__ __forceinline__ float sigf(float x) {
    return 1.0f / (1.0f + expf(-x));
}

// ---- DPP wave64 primitives (proven exact rounds 5-14, absmax 0) ----
__device__ __forceinline__ unsigned wave_max_bcast(unsigned x) {
    unsigned t;
    t = (unsigned)__builtin_amdgcn_update_dpp((int)x, (int)x, 0x111, 0xF, 0xF, false); x = x > t ? x : t;
    t = (unsigned)__builtin_amdgcn_update_dpp((int)x, (int)x, 0x112, 0xF, 0xF, false); x = x > t ? x : t;
    t = (unsigned)__builtin_amdgcn_update_dpp((int)x, (int)x, 0x114, 0xF, 0xF, false); x = x > t ? x : t;
    t = (unsigned)__builtin_amdgcn_update_dpp((int)x, (int)x, 0x118, 0xF, 0xF, false); x = x > t ? x : t;
    t = (unsigned)__builtin_amdgcn_update_dpp((int)x, (int)x, 0x142, 0xF, 0xF, false); x = x > t ? x : t;
    t = (unsigned)__builtin_amdgcn_update_dpp((int)x, (int)x, 0x143, 0xF, 0xF, false); x = x > t ? x : t;
    return (unsigned)__builtin_amdgcn_readlane((int)x, 63);
}

__device__ __forceinline__ unsigned wave_min_bcast(unsigned x) {
    unsigned t;
    t = (unsigned)__builtin_amdgcn_update_dpp((int)x, (int)x, 0x111, 0xF, 0xF, false); x = x < t ? x : t;
    t = (unsigned)__builtin_amdgcn_update_dpp((int)x, (int)x, 0x112, 0xF, 0xF, false); x = x < t ? x : t;
    t = (unsigned)__builtin_amdgcn_update_dpp((int)x, (int)x, 0x114, 0xF, 0xF, false); x = x < t ? x : t;
    t = (unsigned)__builtin_amdgcn_update_dpp((int)x, (int)x, 0x118, 0xF, 0xF, false); x = x < t ? x : t;
    t = (unsigned)__builtin_amdgcn_update_dpp((int)x, (int)x, 0x142, 0xF, 0xF, false); x = x < t ? x : t;
    t = (unsigned)__builtin_amdgcn_update_dpp((int)x, (int)x, 0x143, 0xF, 0xF, false); x = x < t ? x : t;
    return (unsigned)__builtin_amdgcn_readlane((int)x, 63);
}

// Wave64 inclusive +scan (LLVM AtomicOptimizer idiom).
__device__ __forceinline__ unsigned wave_incl_scan(unsigned x) {
    x += (unsigned)__builtin_amdgcn_update_dpp(0, (int)x, 0x111, 0xF, 0xF, false);
    x += (unsigned)__builtin_amdgcn_update_dpp(0, (int)x, 0x112, 0xF, 0xF, false);
    x += (unsigned)__builtin_amdgcn_update_dpp(0, (int)x, 0x114, 0xF, 0xF, false);
    x += (unsigned)__builtin_amdgcn_update_dpp(0, (int)x, 0x118, 0xF, 0xF, false);
    x += (unsigned)__builtin_amdgcn_update_dpp(0, (int)x, 0x142, 0xA, 0xF, false);
    x += (unsigned)__builtin_amdgcn_update_dpp(0, (int)x, 0x143, 0xC, 0xF, false);
    return x;
}

// r13 decode (proven 44.8us) with phase-1 batching deepened 4->8: typical
// tot (~3500 work items / 512 thr = 7 strides) now fits ONE 8-deep load wave
// -> one L3 latency exposure instead of two. Semantics unchanged.
// NOTE (r8/r14 lesson): decode->NMS must remain separate graph nodes; any
// device-wide barrier (grid.sync or spin) costs ~90us on this chip.
__global__ __launch_bounds__(DT) void decode_kernel(
    const float* __restrict__ feats0, const float* __restrict__ feats1,
    float4* __restrict__ boxes, uint2* __restrict__ cands,
    int* __restrict__ counts)
{
    __shared__ unsigned p_gi[DT];
    __shared__ float    p_conf[DT];
    __shared__ int s_npass;
    __shared__ float    s_esc[DSTAGE];
    __shared__ unsigned s_ent[DSTAGE];       // gi | (class<<18)
    __shared__ unsigned short s_lp[DSTAGE];  // per-class local position
    __shared__ int s_n;
    __shared__ int s_cnt[NCLS];
    __shared__ int s_base[NCLS];

    int tid = threadIdx.x;
    if (tid == 0) { s_npass = 0; s_n = 0; }
    if (tid < NCLS) s_cnt[tid] = 0;
    __syncthreads();

    const float* feats;
    int S, base, i;
    float aw0, ah0, aw1, ah1, aw2, ah2;
    if (blockIdx.x < N0 / DT) {
        feats = feats0; S = 96; base = 0;
        i = blockIdx.x * DT + tid;
        aw0 = 81.0f;  ah0 = 82.0f;  aw1 = 135.0f; ah1 = 169.0f; aw2 = 344.0f; ah2 = 319.0f;
    } else {
        feats = feats1; S = 192; base = N0;
        i = (blockIdx.x - N0 / DT) * DT + tid;
        aw0 = 23.0f;  ah0 = 27.0f;  aw1 = 37.0f;  ah1 = 58.0f;  aw2 = 81.0f;  ah2 = 82.0f;
    }

    // ---- phase 0: gate + inline box decode/write for passing anchors ----
    const float* f = feats + (size_t)i * 85;
    float4 head = *reinterpret_cast<const float4*>(f);   // tx,ty,tw,th
    float sconf = sigf(f[4]);
    if (sconf >= 0.6f) {   // sconf < 0.6 => all class scores < 0.6 (exact)
        int sl = atomicAdd(&s_npass, 1);   // <= DT
        p_gi[sl] = (unsigned)(base + i);
        p_conf[sl] = sconf;

        int a = i % 3;
        int cell = i / 3;
        int gx = cell % S;
        int gy = cell / S;

        float Sf = (float)S;
        float inpf = Sf * 32.0f;
        float aw = (a == 0) ? aw0 : ((a == 1) ? aw1 : aw2);
        float ah = (a == 0) ? ah0 : ((a == 1) ? ah1 : ah2);

        float x = (sigf(head.x) + (float)gx) / Sf;
        float y = (sigf(head.y) + (float)gy) / Sf;
        float w = expf(head.z) * aw / inpf;
        float h = expf(head.w) * ah / inpf;

        // yolo_correct_boxes: letterbox constants identical for both layers
        const float OFF = 0.21875f;
        const float SC  = 3072.0f / 1728.0f;
        float yy = (y - OFF) * SC;
        float hh = h * SC;

        boxes[base + i] = make_float4((yy - hh * 0.5f) * 1080.0f,
                                      (x  - w  * 0.5f) * 1920.0f,
                                      (yy + hh * 0.5f) * 1080.0f,
                                      (x  + w  * 0.5f) * 1920.0f);
    }
    __syncthreads();

    int npass = s_npass;

    // ---- phase 1: dense (pass-anchor, 4-class-group) emission, 8-deep MLP ----
    int tot = npass * (NCLS / 4);
    for (int wk0 = tid; wk0 < tot; wk0 += DT * 8) {
        float4   pv[8];
        unsigned gi8[8];
        float    cf[8];
        int      g8[8];
#pragma unroll
        for (int j = 0; j < 8; ++j) {
            int wk = wk0 + j * DT;
            if (wk < tot) {
                int sl = wk / (NCLS / 4);
                int g  = wk - sl * (NCLS / 4);
                gi8[j] = p_gi[sl];
                cf[j] = p_conf[sl];
                g8[j] = g;
                pv[j] = *reinterpret_cast<const float4*>(
                    feats + (size_t)(gi8[j] - (unsigned)base) * 85 + 5 + g * 4);
            }
        }
#pragma unroll
        for (int j = 0; j < 8; ++j) {
            int wk = wk0 + j * DT;
            if (wk < tot) {
#pragma unroll
                for (int q = 0; q < 4; ++q) {
                    float pj = (q == 0) ? pv[j].x : (q == 1) ? pv[j].y
                             : (q == 2) ? pv[j].z : pv[j].w;
                    float s = cf[j] * sigf(pj);
                    if (s >= 0.6f) {
                        int c = g8[j] * 4 + q;
                        int e = atomicAdd(&s_n, 1);
                        int lp = atomicAdd(&s_cnt[c], 1);
                        if (e < DSTAGE) {
                            s_esc[e] = s;
                            s_ent[e] = gi8[j] | ((unsigned)c << 18);
                            s_lp[e] = (unsigned short)lp;
                        }
                    }
                }
            }
        }
    }
    __syncthreads();

    int n = s_n < DSTAGE ? s_n : DSTAGE;

    // ---- phase 2: one reserve atomic per (block,class), padded lines ----
    if (tid < NCLS) {
        int k = s_cnt[tid];
        s_base[tid] = (k > 0) ? atomicAdd(&counts[tid * CNT_STRIDE], k) : 0;
    }
    __syncthreads();

    // ---- phase 3: scatter into reserved slices (no atomics) ----
    for (int e = tid; e < n; e += DT) {
        unsigned ent = s_ent[e];
        int c = ent >> 18;
        int pos = s_base[c] + (int)s_lp[e];
        if (pos < CAP)
            cands[(size_t)c * CAP + pos] =
                make_uint2(__float_as_uint(s_esc[e]), ent & 0x3FFFFu);
    }
}

// One block per class (byte-identical to round 13, proven absmax 0).
__global__ __launch_bounds__(NMS_T) void nms_kernel(
    const float4* __restrict__ boxes, const uint2* __restrict__ cands,
    const int* __restrict__ counts, float* __restrict__ out)
{
    __shared__ int s_hist[NB];
    __shared__ int s_tau;
    __shared__ int s_m;
    __shared__ float4   s_cbox[SCAP];
    __shared__ unsigned s_csc[SCAP];
    __shared__ unsigned s_cix[SCAP];
    __shared__ unsigned char s_alive[CAP];   // fallback only

    int c = blockIdx.x;
    int tid = threadIdx.x;

    int cnt = counts[c * CNT_STRIDE];
    if (cnt > CAP) cnt = CAP;

    const uint2* cl = cands + (size_t)c * CAP;

    // ---- phase 1: histogram on score bits, 4-deep batched ----
    if (tid < NB) s_hist[tid] = 0;
    if (tid == 0) s_m = 0;
    __syncthreads();

    for (int e0 = tid; e0 < cnt; e0 += NMS_T * 4) {
        unsigned sc4[4];
#pragma unroll
        for (int j = 0; j < 4; ++j) {
            int e = e0 + j * NMS_T;
            if (e < cnt) sc4[j] = cl[e].x;
        }
#pragma unroll
        for (int j = 0; j < 4; ++j) {
            int e = e0 + j * NMS_T;
            if (e < cnt)
                atomicAdd(&s_hist[(sc4[j] - 0x3F199999u) >> 15], 1);
        }
    }
    __syncthreads();

    if (tid < 64) {
        // wave 0: tau = max bucket with cum-from-top >= TARGET (exact)
        unsigned acc = 0;
        bool found = false;
        for (int ch = NB / 64 - 1; ch >= 0 && !found; --ch) {
            unsigned h = (unsigned)s_hist[ch * 64 + tid];
            unsigned incl = wave_incl_scan(h);
            unsigned total = (unsigned)__builtin_amdgcn_readlane((int)incl, 63);
            bool ok = acc + (total - incl + h) >= (unsigned)TARGET;
            unsigned long long mk = __ballot(ok);
            if (mk) {
                if (tid == 0) s_tau = ch * 64 + (63 - __builtin_clzll(mk));
                found = true;
            }
            acc += total;
        }
        if (!found && tid == 0) s_tau = 0;   // take all (total < TARGET)
    }
    __syncthreads();

    int tau = s_tau;
    for (int e0 = tid; e0 < cnt; e0 += NMS_T * 4) {
        uint2 v4[4];
#pragma unroll
        for (int j = 0; j < 4; ++j) {
            int e = e0 + j * NMS_T;
            if (e < cnt) v4[j] = cl[e];
        }
#pragma unroll
        for (int j = 0; j < 4; ++j) {
            int e = e0 + j * NMS_T;
            if (e < cnt && (int)((v4[j].x - 0x3F199999u) >> 15) >= tau) {
                int p = atomicAdd(&s_m, 1);
                if (p < SCAP) {
                    s_csc[p] = v4[j].x;
                    s_cix[p] = v4[j].y;
                    s_cbox[p] = boxes[v4[j].y];
                }
            }
        }
    }
    __syncthreads();

    if (tid >= 64) return;          // only wave 0 continues (no more barriers)

    int lane = tid;
    int m = s_m;
    bool need_fb = (m > SCAP);
    if (m > SCAP) m = SCAP;

    float* ob  = out;             // 1600 boxes * 4
    float* os  = out + 6400;      // 1600 scores
    float* ocl = out + 8000;      // 1600 classes (as float)

    int sel = 0;

    if (!need_fb) {
        unsigned scu[4], ixu[4];
        float4 bx[4];
        float  ar[4];
#pragma unroll
        for (int k = 0; k < 4; ++k) {
            int e = lane + k * 64;
            scu[k] = 0u; ixu[k] = 0xFFFFFFFFu;
            bx[k] = make_float4(0.f, 0.f, 0.f, 0.f);
            ar[k] = 0.f;
            if (e < m) {
                scu[k] = s_csc[e];
                ixu[k] = s_cix[e];
                bx[k] = s_cbox[e];
                ar[k] = (bx[k].z - bx[k].x) * (bx[k].w - bx[k].y);
            }
        }

        for (; sel < MAXB; ++sel) {
            unsigned lm = 0u;
#pragma unroll
            for (int k = 0; k < 4; ++k) lm = lm > scu[k] ? lm : scu[k];
            unsigned smax = wave_max_bcast(lm);
            if (smax == 0u) {
                if (m < cnt) need_fb = true;   // compact list exhausted early
                break;
            }
            unsigned li = 0xFFFFFFFFu;
#pragma unroll
            for (int k = 0; k < 4; ++k)
                if (scu[k] == smax && ixu[k] < li) li = ixu[k];
            unsigned bidx = wave_min_bcast(li);

            bool has = false;
            float4 ob_ = make_float4(0.f, 0.f, 0.f, 0.f);
#pragma unroll
            for (int k = 0; k < 4; ++k)
                if (scu[k] == smax && ixu[k] == bidx) { ob_ = bx[k]; has = true; }
            unsigned long long mk = __ballot(has);
            int src = __ffsll((long long)mk) - 1;
            float4 sb;
            sb.x = __int_as_float(__builtin_amdgcn_readlane(__float_as_int(ob_.x), src));
            sb.y = __int_as_float(__builtin_amdgcn_readlane(__float_as_int(ob_.y), src));
            sb.z = __int_as_float(__builtin_amdgcn_readlane(__float_as_int(ob_.z), src));
            sb.w = __int_as_float(__builtin_amdgcn_readlane(__float_as_int(ob_.w), src));
            float area_s = (sb.z - sb.x) * (sb.w - sb.y);

            if (lane == 0) {
                int o = c * MAXB + sel;
                ob[o * 4 + 0] = sb.x; ob[o * 4 + 1] = sb.y;
                ob[o * 4 + 2] = sb.z; ob[o * 4 + 3] = sb.w;
                os[o]  = __uint_as_float(smax);
                ocl[o] = (float)c;
            }

#pragma unroll
            for (int k = 0; k < 4; ++k) {
                if (scu[k] != 0u) {
                    float y1 = fmaxf(sb.x, bx[k].x);
                    float x1 = fmaxf(sb.y, bx[k].y);
                    float y2 = fminf(sb.z, bx[k].z);
                    float x2 = fminf(sb.w, bx[k].w);
                    float inter = fmaxf(y2 - y1, 0.f) * fmaxf(x2 - x1, 0.f);
                    float un = area_s + ar[k] - inter;
                    float iou = (un > 0.f) ? (inter / un) : 0.f;
                    if (iou > 0.5f || ixu[k] == bidx) scu[k] = 0u;
                }
            }
        }
    }

    if (need_fb) {
        // exact full-list greedy NMS from scratch (statistically never taken)
        for (int e = lane; e < cnt; e += 64) s_alive[e] = 1;
        sel = 0;
        for (; sel < MAXB; ++sel) {
            unsigned bs = 0u, bi = 0xFFFFFFFFu;
            for (int e = lane; e < cnt; e += 64) {
                if (s_alive[e]) {
                    uint2 v = cl[e];
                    if (v.x > bs || (v.x == bs && v.y < bi)) { bs = v.x; bi = v.y; }
                }
            }
            unsigned smax = wave_max_bcast(bs);
            if (smax == 0u) break;
            unsigned li = (bs == smax) ? bi : 0xFFFFFFFFu;
            unsigned bidx = wave_min_bcast(li);

            float4 sb = boxes[bidx];
            float area_s = (sb.z - sb.x) * (sb.w - sb.y);

            if (lane == 0) {
                int o = c * MAXB + sel;
                ob[o * 4 + 0] = sb.x; ob[o * 4 + 1] = sb.y;
                ob[o * 4 + 2] = sb.z; ob[o * 4 + 3] = sb.w;
                os[o]  = __uint_as_float(smax);
                ocl[o] = (float)c;
            }

            for (int e = lane; e < cnt; e += 64) {
                if (s_alive[e]) {
                    uint2 v = cl[e];
                    float4 cb = boxes[v.y];
                    float y1 = fmaxf(sb.x, cb.x);
                    float x1 = fmaxf(sb.y, cb.y);
                    float y2 = fminf(sb.z, cb.z);
                    float x2 = fminf(sb.w, cb.w);
                    float inter = fmaxf(y2 - y1, 0.f) * fmaxf(x2 - x1, 0.f);
                    float area_c = (cb.z - cb.x) * (cb.w - cb.y);
                    float un = area_s + area_c - inter;
                    float iou = (un > 0.f) ? (inter / un) : 0.f;
                    if (iou > 0.5f || v.y == bidx) s_alive[e] = 0;
                }
            }
        }
    }

    // invalid slots: zero boxes/scores, class = -1 (lane-parallel)
    for (int q = sel + lane; q < MAXB; q += 64) {
        int o = c * MAXB + q;
        ob[o * 4 + 0] = 0.0f; ob[o * 4 + 1] = 0.0f;
        ob[o * 4 + 2] = 0.0f; ob[o * 4 + 3] = 0.0f;
        os[o]  = 0.0f;
        ocl[o] = -1.0f;
    }
}

extern "C" void kernel_launch(void* const* d_in, const int* in_sizes, int n_in,
                              void* d_out, int out_size, void* d_ws, size_t ws_size,
                              hipStream_t stream) {
    const float* feats0 = (const float*)d_in[0];
    const float* feats1 = (const float*)d_in[1];
    float* out = (float*)d_out;

    char* ws = (char*)d_ws;
    float4* boxes  = (float4*)ws;                      // NTOT*16B = 2,211,840
    int*    counts = (int*)(ws + 2211840);             // 80*16*4B
    uint2*  cands  = (uint2*)(ws + 2211840 + 8192);    // 80*CAP*8B = 5.24MB

    hipMemsetAsync(counts, 0, NCLS * CNT_STRIDE * sizeof(int), stream);

    decode_kernel<<<NTOT / DT, DT, 0, stream>>>(feats0, feats1, boxes, cands, counts);

    nms_kernel<<<NCLS, NMS_T, 0, stream>>>(boxes, cands, counts, out);
}

// Round 16
// 41.647 us; speedup vs baseline: 3.0948x; 1.0118x over previous
//
#include <hip/hip_runtime.h>

#define NCLS 80
#define MAXB 20
#define N0 27648     // 96*96*3
#define N1 110592    // 192*192*3
#define NTOT (N0 + N1)
#define CAP 8192       // per-class candidate capacity in workspace
#define DT 512         // decode block size
#define DSTAGE 3072    // per-block candidate staging (expected ~1122, +59 sigma)
#define CNT_STRIDE 16  // pad class counters to one 64B line each
#define NMS_T 1024
#define NB 256         // score histogram buckets ((bits-0.6f)>>15, max 204)
#define TARGET 64      // top-k cut for fast NMS path (exact via fallback)
#define SCAP 256       // compact-list capacity (4 slots/lane in wave 0)

__device__ __forceinline__ float sigf(float x) {
    return 1.0f / (1.0f + expf(-x));
}

// ---- DPP wave64 primitives (proven exact rounds 5-15, absmax 0) ----
__device__ __forceinline__ unsigned wave_max_bcast(unsigned x) {
    unsigned t;
    t = (unsigned)__builtin_amdgcn_update_dpp((int)x, (int)x, 0x111, 0xF, 0xF, false); x = x > t ? x : t;
    t = (unsigned)__builtin_amdgcn_update_dpp((int)x, (int)x, 0x112, 0xF, 0xF, false); x = x > t ? x : t;
    t = (unsigned)__builtin_amdgcn_update_dpp((int)x, (int)x, 0x114, 0xF, 0xF, false); x = x > t ? x : t;
    t = (unsigned)__builtin_amdgcn_update_dpp((int)x, (int)x, 0x118, 0xF, 0xF, false); x = x > t ? x : t;
    t = (unsigned)__builtin_amdgcn_update_dpp((int)x, (int)x, 0x142, 0xF, 0xF, false); x = x > t ? x : t;
    t = (unsigned)__builtin_amdgcn_update_dpp((int)x, (int)x, 0x143, 0xF, 0xF, false); x = x > t ? x : t;
    return (unsigned)__builtin_amdgcn_readlane((int)x, 63);
}

__device__ __forceinline__ unsigned wave_min_bcast(unsigned x) {
    unsigned t;
    t = (unsigned)__builtin_amdgcn_update_dpp((int)x, (int)x, 0x111, 0xF, 0xF, false); x = x < t ? x : t;
    t = (unsigned)__builtin_amdgcn_update_dpp((int)x, (int)x, 0x112, 0xF, 0xF, false); x = x < t ? x : t;
    t = (unsigned)__builtin_amdgcn_update_dpp((int)x, (int)x, 0x114, 0xF, 0xF, false); x = x < t ? x : t;
    t = (unsigned)__builtin_amdgcn_update_dpp((int)x, (int)x, 0x118, 0xF, 0xF, false); x = x < t ? x : t;
    t = (unsigned)__builtin_amdgcn_update_dpp((int)x, (int)x, 0x142, 0xF, 0xF, false); x = x < t ? x : t;
    t = (unsigned)__builtin_amdgcn_update_dpp((int)x, (int)x, 0x143, 0xF, 0xF, false); x = x < t ? x : t;
    return (unsigned)__builtin_amdgcn_readlane((int)x, 63);
}

// Wave64 inclusive +scan (LLVM AtomicOptimizer idiom).
__device__ __forceinline__ unsigned wave_incl_scan(unsigned x) {
    x += (unsigned)__builtin_amdgcn_update_dpp(0, (int)x, 0x111, 0xF, 0xF, false);
    x += (unsigned)__builtin_amdgcn_update_dpp(0, (int)x, 0x112, 0xF, 0xF, false);
    x += (unsigned)__builtin_amdgcn_update_dpp(0, (int)x, 0x114, 0xF, 0xF, false);
    x += (unsigned)__builtin_amdgcn_update_dpp(0, (int)x, 0x118, 0xF, 0xF, false);
    x += (unsigned)__builtin_amdgcn_update_dpp(0, (int)x, 0x142, 0xA, 0xF, false);
    x += (unsigned)__builtin_amdgcn_update_dpp(0, (int)x, 0x143, 0xC, 0xF, false);
    return x;
}

// r15 decode, unchanged (proven 42.1us / absmax 0).
// NOTE (r8/r14 lesson): decode->NMS must remain separate graph nodes; any
// device-wide barrier (grid.sync or spin) costs ~90us on this chip.
__global__ __launch_bounds__(DT) void decode_kernel(
    const float* __restrict__ feats0, const float* __restrict__ feats1,
    float4* __restrict__ boxes, uint2* __restrict__ cands,
    int* __restrict__ counts)
{
    __shared__ unsigned p_gi[DT];
    __shared__ float    p_conf[DT];
    __shared__ int s_npass;
    __shared__ float    s_esc[DSTAGE];
    __shared__ unsigned s_ent[DSTAGE];       // gi | (class<<18)
    __shared__ unsigned short s_lp[DSTAGE];  // per-class local position
    __shared__ int s_n;
    __shared__ int s_cnt[NCLS];
    __shared__ int s_base[NCLS];

    int tid = threadIdx.x;
    if (tid == 0) { s_npass = 0; s_n = 0; }
    if (tid < NCLS) s_cnt[tid] = 0;
    __syncthreads();

    const float* feats;
    int S, base, i;
    float aw0, ah0, aw1, ah1, aw2, ah2;
    if (blockIdx.x < N0 / DT) {
        feats = feats0; S = 96; base = 0;
        i = blockIdx.x * DT + tid;
        aw0 = 81.0f;  ah0 = 82.0f;  aw1 = 135.0f; ah1 = 169.0f; aw2 = 344.0f; ah2 = 319.0f;
    } else {
        feats = feats1; S = 192; base = N0;
        i = (blockIdx.x - N0 / DT) * DT + tid;
        aw0 = 23.0f;  ah0 = 27.0f;  aw1 = 37.0f;  ah1 = 58.0f;  aw2 = 81.0f;  ah2 = 82.0f;
    }

    // ---- phase 0: gate + inline box decode/write for passing anchors ----
    const float* f = feats + (size_t)i * 85;
    float4 head = *reinterpret_cast<const float4*>(f);   // tx,ty,tw,th
    float sconf = sigf(f[4]);
    if (sconf >= 0.6f) {   // sconf < 0.6 => all class scores < 0.6 (exact)
        int sl = atomicAdd(&s_npass, 1);   // <= DT
        p_gi[sl] = (unsigned)(base + i);
        p_conf[sl] = sconf;

        int a = i % 3;
        int cell = i / 3;
        int gx = cell % S;
        int gy = cell / S;

        float Sf = (float)S;
        float inpf = Sf * 32.0f;
        float aw = (a == 0) ? aw0 : ((a == 1) ? aw1 : aw2);
        float ah = (a == 0) ? ah0 : ((a == 1) ? ah1 : ah2);

        float x = (sigf(head.x) + (float)gx) / Sf;
        float y = (sigf(head.y) + (float)gy) / Sf;
        float w = expf(head.z) * aw / inpf;
        float h = expf(head.w) * ah / inpf;

        // yolo_correct_boxes: letterbox constants identical for both layers
        const float OFF = 0.21875f;
        const float SC  = 3072.0f / 1728.0f;
        float yy = (y - OFF) * SC;
        float hh = h * SC;

        boxes[base + i] = make_float4((yy - hh * 0.5f) * 1080.0f,
                                      (x  - w  * 0.5f) * 1920.0f,
                                      (yy + hh * 0.5f) * 1080.0f,
                                      (x  + w  * 0.5f) * 1920.0f);
    }
    __syncthreads();

    int npass = s_npass;

    // ---- phase 1: dense (pass-anchor, 4-class-group) emission, 8-deep MLP ----
    int tot = npass * (NCLS / 4);
    for (int wk0 = tid; wk0 < tot; wk0 += DT * 8) {
        float4   pv[8];
        unsigned gi8[8];
        float    cf[8];
        int      g8[8];
#pragma unroll
        for (int j = 0; j < 8; ++j) {
            int wk = wk0 + j * DT;
            if (wk < tot) {
                int sl = wk / (NCLS / 4);
                int g  = wk - sl * (NCLS / 4);
                gi8[j] = p_gi[sl];
                cf[j] = p_conf[sl];
                g8[j] = g;
                pv[j] = *reinterpret_cast<const float4*>(
                    feats + (size_t)(gi8[j] - (unsigned)base) * 85 + 5 + g * 4);
            }
        }
#pragma unroll
        for (int j = 0; j < 8; ++j) {
            int wk = wk0 + j * DT;
            if (wk < tot) {
#pragma unroll
                for (int q = 0; q < 4; ++q) {
                    float pj = (q == 0) ? pv[j].x : (q == 1) ? pv[j].y
                             : (q == 2) ? pv[j].z : pv[j].w;
                    float s = cf[j] * sigf(pj);
                    if (s >= 0.6f) {
                        int c = g8[j] * 4 + q;
                        int e = atomicAdd(&s_n, 1);
                        int lp = atomicAdd(&s_cnt[c], 1);
                        if (e < DSTAGE) {
                            s_esc[e] = s;
                            s_ent[e] = gi8[j] | ((unsigned)c << 18);
                            s_lp[e] = (unsigned short)lp;
                        }
                    }
                }
            }
        }
    }
    __syncthreads();

    int n = s_n < DSTAGE ? s_n : DSTAGE;

    // ---- phase 2: one reserve atomic per (block,class), padded lines ----
    if (tid < NCLS) {
        int k = s_cnt[tid];
        s_base[tid] = (k > 0) ? atomicAdd(&counts[tid * CNT_STRIDE], k) : 0;
    }
    __syncthreads();

    // ---- phase 3: scatter into reserved slices (no atomics) ----
    for (int e = tid; e < n; e += DT) {
        unsigned ent = s_ent[e];
        int c = ent >> 18;
        int pos = s_base[c] + (int)s_lp[e];
        if (pos < CAP)
            cands[(size_t)c * CAP + pos] =
                make_uint2(__float_as_uint(s_esc[e]), ent & 0x3FFFFu);
    }
}

// One block per class (r15 body + split-phase compact: sweep collects
// (sc,ix) only; boxes for the <=SCAP winners fetched afterward by all 1024
// threads in one parallel wave instead of dependent scatters in the sweep).
__global__ __launch_bounds__(NMS_T) void nms_kernel(
    const float4* __restrict__ boxes, const uint2* __restrict__ cands,
    const int* __restrict__ counts, float* __restrict__ out)
{
    __shared__ int s_hist[NB];
    __shared__ int s_tau;
    __shared__ int s_m;
    __shared__ float4   s_cbox[SCAP];
    __shared__ unsigned s_csc[SCAP];
    __shared__ unsigned s_cix[SCAP];
    __shared__ unsigned char s_alive[CAP];   // fallback only

    int c = blockIdx.x;
    int tid = threadIdx.x;

    int cnt = counts[c * CNT_STRIDE];
    if (cnt > CAP) cnt = CAP;

    const uint2* cl = cands + (size_t)c * CAP;

    // ---- phase 1: histogram on score bits, 4-deep batched ----
    if (tid < NB) s_hist[tid] = 0;
    if (tid == 0) s_m = 0;
    __syncthreads();

    for (int e0 = tid; e0 < cnt; e0 += NMS_T * 4) {
        unsigned sc4[4];
#pragma unroll
        for (int j = 0; j < 4; ++j) {
            int e = e0 + j * NMS_T;
            if (e < cnt) sc4[j] = cl[e].x;
        }
#pragma unroll
        for (int j = 0; j < 4; ++j) {
            int e = e0 + j * NMS_T;
            if (e < cnt)
                atomicAdd(&s_hist[(sc4[j] - 0x3F199999u) >> 15], 1);
        }
    }
    __syncthreads();

    if (tid < 64) {
        // wave 0: tau = max bucket with cum-from-top >= TARGET (exact)
        unsigned acc = 0;
        bool found = false;
        for (int ch = NB / 64 - 1; ch >= 0 && !found; --ch) {
            unsigned h = (unsigned)s_hist[ch * 64 + tid];
            unsigned incl = wave_incl_scan(h);
            unsigned total = (unsigned)__builtin_amdgcn_readlane((int)incl, 63);
            bool ok = acc + (total - incl + h) >= (unsigned)TARGET;
            unsigned long long mk = __ballot(ok);
            if (mk) {
                if (tid == 0) s_tau = ch * 64 + (63 - __builtin_clzll(mk));
                found = true;
            }
            acc += total;
        }
        if (!found && tid == 0) s_tau = 0;   // take all (total < TARGET)
    }
    __syncthreads();

    // ---- phase 2a: compact (sc, ix) only — no dependent box loads ----
    int tau = s_tau;
    for (int e0 = tid; e0 < cnt; e0 += NMS_T * 4) {
        uint2 v4[4];
#pragma unroll
        for (int j = 0; j < 4; ++j) {
            int e = e0 + j * NMS_T;
            if (e < cnt) v4[j] = cl[e];
        }
#pragma unroll
        for (int j = 0; j < 4; ++j) {
            int e = e0 + j * NMS_T;
            if (e < cnt && (int)((v4[j].x - 0x3F199999u) >> 15) >= tau) {
                int p = atomicAdd(&s_m, 1);
                if (p < SCAP) {
                    s_csc[p] = v4[j].x;
                    s_cix[p] = v4[j].y;
                }
            }
        }
    }
    __syncthreads();

    // ---- phase 2b: fetch winner boxes in ONE parallel wave ----
    int mm = s_m < SCAP ? s_m : SCAP;
    for (int p = tid; p < mm; p += NMS_T)
        s_cbox[p] = boxes[s_cix[p]];
    __syncthreads();

    if (tid >= 64) return;          // only wave 0 continues (no more barriers)

    int lane = tid;
    int m = s_m;
    bool need_fb = (m > SCAP);
    if (m > SCAP) m = SCAP;

    float* ob  = out;             // 1600 boxes * 4
    float* os  = out + 6400;      // 1600 scores
    float* ocl = out + 8000;      // 1600 classes (as float)

    int sel = 0;

    if (!need_fb) {
        unsigned scu[4], ixu[4];
        float4 bx[4];
        float  ar[4];
#pragma unroll
        for (int k = 0; k < 4; ++k) {
            int e = lane + k * 64;
            scu[k] = 0u; ixu[k] = 0xFFFFFFFFu;
            bx[k] = make_float4(0.f, 0.f, 0.f, 0.f);
            ar[k] = 0.f;
            if (e < m) {
                scu[k] = s_csc[e];
                ixu[k] = s_cix[e];
                bx[k] = s_cbox[e];
                ar[k] = (bx[k].z - bx[k].x) * (bx[k].w - bx[k].y);
            }
        }

        for (; sel < MAXB; ++sel) {
            unsigned lm = 0u;
#pragma unroll
            for (int k = 0; k < 4; ++k) lm = lm > scu[k] ? lm : scu[k];
            unsigned smax = wave_max_bcast(lm);
            if (smax == 0u) {
                if (m < cnt) need_fb = true;   // compact list exhausted early
                break;
            }
            unsigned li = 0xFFFFFFFFu;
#pragma unroll
            for (int k = 0; k < 4; ++k)
                if (scu[k] == smax && ixu[k] < li) li = ixu[k];
            unsigned bidx = wave_min_bcast(li);

            bool has = false;
            float4 ob_ = make_float4(0.f, 0.f, 0.f, 0.f);
#pragma unroll
            for (int k = 0; k < 4; ++k)
                if (scu[k] == smax && ixu[k] == bidx) { ob_ = bx[k]; has = true; }
            unsigned long long mk = __ballot(has);
            int src = __ffsll((long long)mk) - 1;
            float4 sb;
            sb.x = __int_as_float(__builtin_amdgcn_readlane(__float_as_int(ob_.x), src));
            sb.y = __int_as_float(__builtin_amdgcn_readlane(__float_as_int(ob_.y), src));
            sb.z = __int_as_float(__builtin_amdgcn_readlane(__float_as_int(ob_.z), src));
            sb.w = __int_as_float(__builtin_amdgcn_readlane(__float_as_int(ob_.w), src));
            float area_s = (sb.z - sb.x) * (sb.w - sb.y);

            if (lane == 0) {
                int o = c * MAXB + sel;
                ob[o * 4 + 0] = sb.x; ob[o * 4 + 1] = sb.y;
                ob[o * 4 + 2] = sb.z; ob[o * 4 + 3] = sb.w;
                os[o]  = __uint_as_float(smax);
                ocl[o] = (float)c;
            }

#pragma unroll
            for (int k = 0; k < 4; ++k) {
                if (scu[k] != 0u) {
                    float y1 = fmaxf(sb.x, bx[k].x);
                    float x1 = fmaxf(sb.y, bx[k].y);
                    float y2 = fminf(sb.z, bx[k].z);
                    float x2 = fminf(sb.w, bx[k].w);
                    float inter = fmaxf(y2 - y1, 0.f) * fmaxf(x2 - x1, 0.f);
                    float un = area_s + ar[k] - inter;
                    float iou = (un > 0.f) ? (inter / un) : 0.f;
                    if (iou > 0.5f || ixu[k] == bidx) scu[k] = 0u;
                }
            }
        }
    }

    if (need_fb) {
        // exact full-list greedy NMS from scratch (statistically never taken)
        for (int e = lane; e < cnt; e += 64) s_alive[e] = 1;
        sel = 0;
        for (; sel < MAXB; ++sel) {
            unsigned bs = 0u, bi = 0xFFFFFFFFu;
            for (int e = lane; e < cnt; e += 64) {
                if (s_alive[e]) {
                    uint2 v = cl[e];
                    if (v.x > bs || (v.x == bs && v.y < bi)) { bs = v.x; bi = v.y; }
                }
            }
            unsigned smax = wave_max_bcast(bs);
            if (smax == 0u) break;
            unsigned li = (bs == smax) ? bi : 0xFFFFFFFFu;
            unsigned bidx = wave_min_bcast(li);

            float4 sb = boxes[bidx];
            float area_s = (sb.z - sb.x) * (sb.w - sb.y);

            if (lane == 0) {
                int o = c * MAXB + sel;
                ob[o * 4 + 0] = sb.x; ob[o * 4 + 1] = sb.y;
                ob[o * 4 + 2] = sb.z; ob[o * 4 + 3] = sb.w;
                os[o]  = __uint_as_float(smax);
                ocl[o] = (float)c;
            }

            for (int e = lane; e < cnt; e += 64) {
                if (s_alive[e]) {
                    uint2 v = cl[e];
                    float4 cb = boxes[v.y];
                    float y1 = fmaxf(sb.x, cb.x);
                    float x1 = fmaxf(sb.y, cb.y);
                    float y2 = fminf(sb.z, cb.z);
                    float x2 = fminf(sb.w, cb.w);
                    float inter = fmaxf(y2 - y1, 0.f) * fmaxf(x2 - x1, 0.f);
                    float area_c = (cb.z - cb.x) * (cb.w - cb.y);
                    float un = area_s + area_c - inter;
                    float iou = (un > 0.f) ? (inter / un) : 0.f;
                    if (iou > 0.5f || v.y == bidx) s_alive[e] = 0;
                }
            }
        }
    }

    // invalid slots: zero boxes/scores, class = -1 (lane-parallel)
    for (int q = sel + lane; q < MAXB; q += 64) {
        int o = c * MAXB + q;
        ob[o * 4 + 0] = 0.0f; ob[o * 4 + 1] = 0.0f;
        ob[o * 4 + 2] = 0.0f; ob[o * 4 + 3] = 0.0f;
        os[o]  = 0.0f;
        ocl[o] = -1.0f;
    }
}

extern "C" void kernel_launch(void* const* d_in, const int* in_sizes, int n_in,
                              void* d_out, int out_size, void* d_ws, size_t ws_size,
                              hipStream_t stream) {
    const float* feats0 = (const float*)d_in[0];
    const float* feats1 = (const float*)d_in[1];
    float* out = (float*)d_out;

    char* ws = (char*)d_ws;
    float4* boxes  = (float4*)ws;                      // NTOT*16B = 2,211,840
    int*    counts = (int*)(ws + 2211840);             // 80*16*4B = 5120
    uint2*  cands  = (uint2*)(ws + 2211840 + 8192);    // 80*CAP*8B = 5.24MB

    hipMemsetAsync(counts, 0, NCLS * CNT_STRIDE * sizeof(int), stream);

    decode_kernel<<<NTOT / DT, DT, 0, stream>>>(feats0, feats1, boxes, cands, counts);

    nms_kernel<<<NCLS, NMS_T, 0, stream>>>(boxes, cands, counts, out);
}